// Round 4
// baseline (235.619 us; speedup 1.0000x reference)
//
#include <hip/hip_runtime.h>
#include <stdint.h>

// Per-row top-K magnitude masking, exact. x: (4096, 8192) fp32, K=819.
// One 256-thread block per row; row in registers (8 x uint4 / thread).
// Phase 1: 11-bit (2048-bin) LDS histogram on abs-bit-pattern bits 30..20,
//          block suffix-scan -> winning bin d1 + rank-within-bin.
// Then: compact the ~200 candidates (keys matching d1) into an LDS list
//       (aliased onto the dead histogram), and one wave refines the low
//       20 bits exactly via ballot/popc -- no more full-row phases.
// Fallback (n > CAP, impossible for this Gaussian input but kept for
// correctness): distributed per-bit count over the register-held row.

constexpr int NCOLS = 8192;
constexpr int TPB   = 256;
constexpr int V4    = NCOLS / 4;   // 2048 uint4 per row
constexpr int VPT   = V4 / TPB;    // 8 uint4 per thread

constexpr int B1  = 2048;          // phase-1 bins (key bits 30..20)
constexpr int C1  = 2;             // histogram copies (2 waves per copy)
constexpr int PAD = 8;
constexpr int S1  = B1 + PAD;      // 2056 words per copy
constexpr int CAP = 512;           // candidate-list capacity (8 items/lane)

typedef uint32_t u32x4 __attribute__((ext_vector_type(4)));  // native vec for NT store

struct alignas(16) Shared {
  uint32_t hist[C1 * S1];          // phase-1 histogram; candidate list after
  uint32_t wavered[4];             // cross-wave scan/reduce scratch
  uint32_t digit;                  // winning 11-bit digit
  uint32_t rem;                    // rank within winning bin (1-based)
  uint32_t thrlow;                 // refined low 20 bits of threshold
};

__global__ __launch_bounds__(TPB) void topk_row_kernel(const float* __restrict__ x,
                                                       float* __restrict__ out,
                                                       int K) {
  __shared__ Shared sh;
  const int row  = blockIdx.x;
  const int tid  = threadIdx.x;
  const int lane = tid & 63;
  const int wave = tid >> 6;

  const uint4* xr = (const uint4*)(x) + (size_t)row * V4;
  uint4 v[VPT];
#pragma unroll
  for (int i = 0; i < VPT; ++i) v[i] = xr[tid + i * TPB];

  // ---- Phase 1: 2048-bin histogram of key>>20 (key = abs bit pattern) ----
  uint4* hz = (uint4*)sh.hist;
  for (int i = tid; i < (C1 * S1) / 4; i += TPB) hz[i] = make_uint4(0u, 0u, 0u, 0u);
  __syncthreads();                                   // (A)

  uint32_t* h = &sh.hist[(wave >> 1) * S1];
#pragma unroll
  for (int i = 0; i < VPT; ++i) {
    atomicAdd(&h[(v[i].x & 0x7fffffffu) >> 20], 1u);
    atomicAdd(&h[(v[i].y & 0x7fffffffu) >> 20], 1u);
    atomicAdd(&h[(v[i].z & 0x7fffffffu) >> 20], 1u);
    atomicAdd(&h[(v[i].w & 0x7fffffffu) >> 20], 1u);
  }
  __syncthreads();                                   // (B)

  // Combine copies: thread owns bins [tid*8, tid*8+8).
  uint32_t hb[8];
  {
    const uint4* p0 = (const uint4*)&sh.hist[0 * S1 + tid * 8];
    const uint4* p1 = (const uint4*)&sh.hist[1 * S1 + tid * 8];
    uint4 a0 = p0[0], a1 = p0[1], b0 = p1[0], b1 = p1[1];
    hb[0] = a0.x + b0.x; hb[1] = a0.y + b0.y; hb[2] = a0.z + b0.z; hb[3] = a0.w + b0.w;
    hb[4] = a1.x + b1.x; hb[5] = a1.y + b1.y; hb[6] = a1.z + b1.z; hb[7] = a1.w + b1.w;
  }
  uint32_t L = hb[0] + hb[1] + hb[2] + hb[3] + hb[4] + hb[5] + hb[6] + hb[7];

  // Wave inclusive suffix-scan of L, then cross-wave combine.
  uint32_t suf = L;
#pragma unroll
  for (int off = 1; off < 64; off <<= 1) {
    uint32_t o = __shfl_down(suf, off, 64);
    suf += (lane + off < 64) ? o : 0u;
  }
  if (lane == 0) sh.wavered[wave] = suf;
  __syncthreads();                                   // (C)

  uint32_t rem = (uint32_t)K;
  {
    uint32_t addw = 0;
#pragma unroll
    for (int w = 0; w < 4; ++w) addw += (w > wave) ? sh.wavered[w] : 0u;
    suf += addw;                                     // S(first own bin)
    uint32_t s = suf - L;                            // S(own last bin + 1)
#pragma unroll
    for (int j = 7; j >= 0; --j) {
      uint32_t snx = s;                              // S(bin+1)
      s += hb[j];                                    // S(bin)
      if (s >= rem && snx < rem) {
        sh.digit = (uint32_t)(tid * 8 + j);
        sh.rem   = rem - snx;
      }
    }
  }
  __syncthreads();                                   // (D)
  const uint32_t d1 = sh.digit;
  rem = sh.rem;

  // ---- Compact candidates (key>>20 == d1) into list aliased on hist ----
  uint32_t m = 0;
#pragma unroll
  for (int i = 0; i < VPT; ++i) {
    m += ((v[i].x & 0x7fffffffu) >> 20) == d1;
    m += ((v[i].y & 0x7fffffffu) >> 20) == d1;
    m += ((v[i].z & 0x7fffffffu) >> 20) == d1;
    m += ((v[i].w & 0x7fffffffu) >> 20) == d1;
  }
  uint32_t inc = m;
#pragma unroll
  for (int off = 1; off < 64; off <<= 1) {
    uint32_t o = __shfl_up(inc, off, 64);
    inc += (lane >= off) ? o : 0u;
  }
  uint32_t excl = inc - m;
  if (lane == 63) sh.wavered[wave] = inc;            // wave total
  __syncthreads();                                   // (E)

  uint32_t n = 0, base = 0;
#pragma unroll
  for (int w = 0; w < 4; ++w) {
    uint32_t t = sh.wavered[w];
    n += t;
    base += (w < wave) ? t : 0u;
  }
  {
    uint32_t idx = base + excl;
#pragma unroll
    for (int i = 0; i < VPT; ++i) {
      uint32_t a;
      a = v[i].x & 0x7fffffffu; if ((a >> 20) == d1) { if (idx < CAP) sh.hist[idx] = a; ++idx; }
      a = v[i].y & 0x7fffffffu; if ((a >> 20) == d1) { if (idx < CAP) sh.hist[idx] = a; ++idx; }
      a = v[i].z & 0x7fffffffu; if ((a >> 20) == d1) { if (idx < CAP) sh.hist[idx] = a; ++idx; }
      a = v[i].w & 0x7fffffffu; if ((a >> 20) == d1) { if (idx < CAP) sh.hist[idx] = a; ++idx; }
    }
  }
  __syncthreads();                                   // (F)

  if (n <= CAP) {
    // ---- Single-wave exact refinement of the low 20 bits ----
    if (wave == 0) {
      uint32_t key[8];
      uint32_t actm = 0;
#pragma unroll
      for (int j = 0; j < 8; ++j) {
        int id = lane + 64 * j;
        bool ok = id < (int)n;
        key[j] = ok ? sh.hist[id] : 0u;
        actm |= ok ? (1u << j) : 0u;
      }
      uint32_t p = 0, r = rem;
      for (int b = 19; b >= 0; --b) {
        uint32_t c1 = 0, tm = 0;
#pragma unroll
        for (int j = 0; j < 8; ++j) {
          bool t = ((actm >> j) & 1u) && ((key[j] >> b) & 1u);
          tm |= t ? (1u << j) : 0u;
          c1 += (uint32_t)__popcll(__ballot(t));
        }
        if (c1 >= r) { p |= (1u << b); actm = tm; }
        else         { r -= c1; actm &= ~tm; }
      }
      if (lane == 0) sh.thrlow = p;
    }
    __syncthreads();                                 // (G)
  } else {
    // ---- Fallback: distributed per-bit refinement (correct for any input) ----
    uint32_t p = 0, r = rem;
    for (int b = 19; b >= 0; --b) {
      const uint32_t msk  = 0x7fffffffu & ~((1u << (b + 1)) - 1u);
      const uint32_t want = ((d1 << 20) | p) & msk;
      uint32_t c = 0;
#pragma unroll
      for (int i = 0; i < VPT; ++i) {
        c += (((v[i].x & 0x7fffffffu) & msk) == want) && ((v[i].x >> b) & 1u);
        c += (((v[i].y & 0x7fffffffu) & msk) == want) && ((v[i].y >> b) & 1u);
        c += (((v[i].z & 0x7fffffffu) & msk) == want) && ((v[i].z >> b) & 1u);
        c += (((v[i].w & 0x7fffffffu) & msk) == want) && ((v[i].w >> b) & 1u);
      }
      uint32_t t = c;
#pragma unroll
      for (int off = 1; off < 64; off <<= 1) {
        uint32_t o = __shfl_down(t, off, 64);
        t += (lane + off < 64) ? o : 0u;
      }
      if (lane == 0) sh.wavered[wave] = t;
      __syncthreads();
      uint32_t c1 = sh.wavered[0] + sh.wavered[1] + sh.wavered[2] + sh.wavered[3];
      if (c1 >= r) p |= (1u << b);
      else         r -= c1;
      __syncthreads();
    }
    if (tid == 0) sh.thrlow = p;
    __syncthreads();
  }

  const uint32_t thr = (d1 << 20) | sh.thrlow;       // exact K-th largest |x| bits

  u32x4* outr = (u32x4*)(out) + (size_t)row * V4;
#pragma unroll
  for (int i = 0; i < VPT; ++i) {
    uint4 o = v[i];
    u32x4 w;
    w.x = ((o.x & 0x7fffffffu) >= thr) ? o.x : 0u;
    w.y = ((o.y & 0x7fffffffu) >= thr) ? o.y : 0u;
    w.z = ((o.z & 0x7fffffffu) >= thr) ? o.z : 0u;
    w.w = ((o.w & 0x7fffffffu) >= thr) ? o.w : 0u;
    __builtin_nontemporal_store(w, &outr[tid + i * TPB]);
  }
}

extern "C" void kernel_launch(void* const* d_in, const int* in_sizes, int n_in,
                              void* d_out, int out_size, void* d_ws, size_t ws_size,
                              hipStream_t stream) {
  (void)n_in; (void)out_size; (void)d_ws; (void)ws_size;
  const float* x = (const float*)d_in[0];
  float* out = (float*)d_out;
  const int rows = in_sizes[0] / NCOLS;
  const int K = (int)(0.1 * NCOLS + 0.5);  // round(819.2) = 819
  topk_row_kernel<<<rows, TPB, 0, stream>>>(x, out, K);
}